// Round 16
// baseline (214.821 us; speedup 1.0000x reference)
//
#include <hip/hip_runtime.h>
#include <hip/hip_bf16.h>

// Problem constants (match reference setup_inputs)
constexpr int Bc  = 32;
constexpr int Nc  = 2048;
constexpr int Hc  = 128;
constexpr int H4c = 512;
constexpr int BNc = Bc * Nc;   // 65536 rows

typedef __attribute__((ext_vector_type(8))) short short8;
typedef __attribute__((ext_vector_type(4))) float f32x4;

// clamp-free: v_exp saturates to 0/inf, forms below stay finite/correct
__device__ __forceinline__ float sigf(float x)  { return 1.f / (1.f + __expf(-x)); }
__device__ __forceinline__ float tanh_(float x) { return 1.f - 2.f / (__expf(2.f * x) + 1.f); }

// f32 -> bf16 bits (RNE)
__device__ __forceinline__ unsigned short bfu(float f) {
    union { float f; unsigned u; } a; a.f = f;
    unsigned u = a.u;
    return (unsigned short)((u + 0x7FFFu + ((u >> 16) & 1u)) >> 16);
}
__device__ __forceinline__ float bf2f(unsigned short u) {
    union { unsigned u; float f; } a; a.u = ((unsigned)u) << 16;
    return a.f;
}
// HW packed conversion: lo -> bits[15:0], hi -> bits[31:16], RNE
__device__ __forceinline__ unsigned cvtpk(float lo, float hi) {
    unsigned r;
    asm("v_cvt_pk_bf16_f32 %0, %1, %2" : "=v"(r) : "v"(lo), "v"(hi));
    return r;
}

// A-tile (dbuf staging): row stride 80 B (64 B data + 16 pad).
__device__ __forceinline__ int a_off(int buf, int row, int byte) {
    return buf * 5120 + row * 80 + byte;
}
// Cs tile: 64 rows x 32 units of 16 B, XOR swizzle.
__device__ __forceinline__ int cs_off(int row, int unit) {
    return row * 512 + ((unit ^ (row & 7)) << 4);
}

// ---------------------------------------------------------------------------
// Weight prep -> fragment-major: WF[ct][ks][lane][e], col = ct*16 + (lane&15),
// k = ks*32 + (lane>>4)*8 + e. Also clears head[] (-1).
// ---------------------------------------------------------------------------
__global__ __launch_bounds__(256) void prep_kernel(
    const float* __restrict__ Wx0, const float* __restrict__ Wh0,
    const float* __restrict__ Wx1, const float* __restrict__ Wh1,
    unsigned short* __restrict__ W0F, unsigned short* __restrict__ W1F,
    int* __restrict__ head)
{
    int idx = blockIdx.x * 256 + threadIdx.x;   // 0..16383 = (ct,ks,lane)
    int4 m1 = { -1, -1, -1, -1 };
    ((int4*)head)[idx] = m1;                    // 16384 x int4 = 65536 ints

    int ct = idx >> 9, ks = (idx >> 6) & 7, lane = idx & 63;
    int col = ct * 16 + (lane & 15);
    unsigned short* p0 = W0F + (size_t)idx * 8;
    unsigned short* p1 = W1F + (size_t)idx * 8;
    #pragma unroll
    for (int e = 0; e < 8; ++e) {
        int k = ks * 32 + (lane >> 4) * 8 + e;
        float v0 = (k < 128) ? Wx0[k * 512 + col] : Wh0[(k - 128) * 512 + col];
        float v1 = (k < 128) ? Wx1[k * 512 + col] : Wh1[(k - 128) * 512 + col];
        p0[e] = bfu(v0);
        p1[e] = bfu(v1);
    }
}

// ---------------------------------------------------------------------------
// gemm0: 512 thr / 8 waves / 64 rows x all 512 cols — r13/r15 structure.
// NEW: computes the cols-0..255 HALF of the decision dot-products from its
// own Cs tile (LDS-only) and writes w_part[row] = {pr0,pr1,pb0,pb1}.
// ---------------------------------------------------------------------------
__global__ __launch_bounds__(512, 4) void gemm0_kernel(
    const float* __restrict__ x_in,  const float* __restrict__ c0_in,
    const float* __restrict__ h0_in,
    const unsigned short* __restrict__ W0F, const float* __restrict__ b0,
    const float* __restrict__ rW, const float* __restrict__ bW,
    const int* __restrict__ exit_i, const int* __restrict__ raise_i,
    unsigned short* __restrict__ contrib, float4* __restrict__ w_part)
{
    __shared__ __align__(16) char Ab[10240];   // A dbuf; later dec weights
    __shared__ __align__(16) char Cs[32768];   // 64 rows x 256 bf16 restage

    const int t    = threadIdx.x;
    const int w    = t >> 6, l = t & 63, lr = l & 15, lg = l >> 4;
    const int row0 = blockIdx.x * 64;
    const int bidx = row0 >> 11;
    const int eb   = exit_i[bidx];
    const int rbn  = raise_i[bidx];
    const int j    = w * 16 + lr;

    const int srow = t >> 3, sfq = t & 7;
#define STAGE0(c, bi)                                                          \
    {                                                                          \
        const float* sp = ((c) < 4 ? x_in : h0_in)                             \
            + (size_t)(row0 + srow) * Hc + ((c) & 3) * 32 + sfq * 4;           \
        float4 v = *(const float4*)sp;                                         \
        uint2 b2 = { cvtpk(v.x, v.y), cvtpk(v.z, v.w) };                       \
        *(uint2*)(Ab + a_off(bi, srow, sfq * 8)) = b2;                         \
    }

    f32x4 acc[4][4];
    #pragma unroll
    for (int g = 0; g < 4; ++g) {
        float bv = b0[g * 128 + j];
        f32x4 vv = {bv, bv, bv, bv};
        #pragma unroll
        for (int mt = 0; mt < 4; ++mt) acc[mt][g] = vv;
    }

    STAGE0(0, 0);
    short8 bn[4];
    #pragma unroll
    for (int g = 0; g < 4; ++g)
        bn[g] = *(const short8*)(W0F + ((size_t)((g * 8 + w) * 8) * 64 + l) * 8);
    #pragma unroll
    for (int c = 0; c < 8; ++c) {
        __syncthreads();
        short8 bc[4];
        #pragma unroll
        for (int g = 0; g < 4; ++g) bc[g] = bn[g];
        if (c < 7) {
            STAGE0(c + 1, (c + 1) & 1);
            #pragma unroll
            for (int g = 0; g < 4; ++g)
                bn[g] = *(const short8*)(W0F + ((size_t)((g * 8 + w) * 8 + c + 1) * 64 + l) * 8);
        }
        short8 a[4];
        #pragma unroll
        for (int mt = 0; mt < 4; ++mt)
            a[mt] = *(const short8*)(Ab + a_off(c & 1, mt * 16 + lr, lg * 16));
        #pragma unroll
        for (int mt = 0; mt < 4; ++mt)
            #pragma unroll
            for (int g = 0; g < 4; ++g)
                acc[mt][g] = __builtin_amdgcn_mfma_f32_16x16x32_bf16(
                    a[mt], bc[g], acc[mt][g], 0, 0, 0);
    }

    // ---- stage dec-weight FIRST halves into Ab (safe: buf0 last read at
    //      chunk 6, all waves passed the chunk-7 barrier) ----
    float* dwA = (float*)Ab;   // [0..511]=rW rows 0..255, [512..1023]=bW rows 0..255
    if (t < 128)      ((float4*)dwA)[t]       = ((const float4*)rW)[t];
    else if (t < 256) ((float4*)dwA)[t]       = ((const float4*)bW)[t - 128];

    // ---- epilogue: LSTM cell 0 -> Cs (inline loads, no arrays) ----
    #pragma unroll
    for (int mt = 0; mt < 4; ++mt) {
        #pragma unroll
        for (int rr = 0; rr < 4; ++rr) {
            const int row  = mt * 16 + lg * 4 + rr;
            const int grow = row0 + row;
            const int n    = grow & (Nc - 1);
            float cold = c0_in[(size_t)grow * Hc + j];
            float ig = sigf(acc[mt][0][rr]);
            float fg = sigf(acc[mt][1][rr]);
            float gv = tanh_(acc[mt][2][rr]);
            float og = sigf(acc[mt][3][rr]);
            float cn = fg * cold + ig * gv;
            float hn = og * tanh_(cn);
            const bool keep = (n == eb) || (n == rbn);
            float cw = keep ? cold : cn;
            float hw = hn;
            if (keep) hw = h0_in[(size_t)grow * Hc + j];   // rare (2 rows/batch)
            *(unsigned short*)(Cs + cs_off(row, j >> 3) + (j & 7) * 2)        = bfu(cw);
            *(unsigned short*)(Cs + cs_off(row, 16 + (j >> 3)) + (j & 7) * 2) = bfu(hw);
        }
    }
    __syncthreads();   // Cs + dwA ready
    // Cs -> contrib cols 0..255 (coalesced 16B stores)
    #pragma unroll
    for (int i = 0; i < 4; ++i) {
        const int idx = i * 512 + t;
        const int r = idx >> 5, u = idx & 31;
        short8 v = *(const short8*)(Cs + cs_off(r, u));
        *(short8*)(contrib + (size_t)(row0 + r) * H4c + u * 8) = v;
    }

    // ---- dec-head partial (cols 0..255, pure LDS): 8 lanes/row ----
    {
        const int r8 = l >> 3, s = l & 7;
        const int row  = w * 8 + r8;
        const int grow = row0 + row;
        float pr0 = 0.f, pr1 = 0.f, pb0 = 0.f, pb1 = 0.f;
        if (s < 4) {
            #pragma unroll
            for (int cu = 0; cu < 8; ++cu) {
                short8 ev = *(const short8*)(Cs + cs_off(row, s * 8 + cu));
                const int col0 = s * 64 + cu * 8;
                const float4* rp = (const float4*)(dwA + col0 * 2);
                const float4* bp = (const float4*)(dwA + 512 + col0 * 2);
                #pragma unroll
                for (int q = 0; q < 4; ++q) {
                    float4 rv = rp[q], bv = bp[q];
                    float e0 = bf2f((unsigned short)ev[q * 2]);
                    float e1 = bf2f((unsigned short)ev[q * 2 + 1]);
                    pr0 += e0 * rv.x + e1 * rv.z;
                    pr1 += e0 * rv.y + e1 * rv.w;
                    pb0 += e0 * bv.x + e1 * bv.z;
                    pb1 += e0 * bv.y + e1 * bv.w;
                }
            }
        }
        #pragma unroll
        for (int m = 1; m < 8; m <<= 1) {
            pr0 += __shfl_xor(pr0, m);
            pr1 += __shfl_xor(pr1, m);
            pb0 += __shfl_xor(pb0, m);
            pb1 += __shfl_xor(pb1, m);
        }
        if (s == 0) {
            float4 wp = { pr0, pr1, pb0, pb1 };
            w_part[grow] = wp;
        }
    }
#undef STAGE0
}

// ---------------------------------------------------------------------------
// gemm1: r13 structure; A = [h0n (bf16 from contrib cols 128..255) | h1
// (f32->bf16)] via chunked dbuf staging. Epilogue: LSTM cell 1 ->
// contrib[:,256:512] + dec head SECOND half (cols 256..511, LDS-only)
// combined with w_part — zero global contrib re-reads.
// ---------------------------------------------------------------------------
__global__ __launch_bounds__(512, 4) void gemm1_kernel(
    const unsigned short* __restrict__ contrib_r, const float* __restrict__ c1_in,
    const float* __restrict__ h1_in,
    const unsigned short* __restrict__ W1F, const float* __restrict__ b1,
    const float* __restrict__ rW, const float* __restrict__ rbv,
    const float* __restrict__ bW, const float* __restrict__ bbv,
    const float* __restrict__ ip_in, const float4* __restrict__ w_part,
    const int* __restrict__ exit_i, const int* __restrict__ raise_i,
    unsigned short* __restrict__ contrib, float* __restrict__ w_all)
{
    __shared__ __align__(16) char Ab[10240];   // A dbuf; later dec weights
    __shared__ __align__(16) char Cs[32768];   // 64 rows x 256 bf16 restage

    const int t    = threadIdx.x;
    const int w    = t >> 6, l = t & 63, lr = l & 15, lg = l >> 4;
    const int row0 = blockIdx.x * 64;
    const int bidx = row0 >> 11;
    const int eb   = exit_i[bidx];
    const int rbn  = raise_i[bidx];
    const int j    = w * 16 + lr;

    const int srow = t >> 3, sfq = t & 7;
    // chunk c: c<4 -> h0n bf16 from contrib cols 128+c*32.. ; c>=4 -> h1 f32
#define STAGE1(c, bi)                                                          \
    {                                                                          \
        if ((c) < 4) {                                                         \
            ushort4 v = *(const ushort4*)(contrib_r                            \
                + (size_t)(row0 + srow) * H4c + 128 + ((c) & 3) * 32 + sfq * 4); \
            *(ushort4*)(Ab + a_off(bi, srow, sfq * 8)) = v;                    \
        } else {                                                               \
            const float* sp = h1_in + (size_t)(row0 + srow) * Hc               \
                + ((c) & 3) * 32 + sfq * 4;                                    \
            float4 v = *(const float4*)sp;                                     \
            uint2 b2 = { cvtpk(v.x, v.y), cvtpk(v.z, v.w) };                   \
            *(uint2*)(Ab + a_off(bi, srow, sfq * 8)) = b2;                     \
        }                                                                      \
    }

    f32x4 acc[4][4];
    #pragma unroll
    for (int g = 0; g < 4; ++g) {
        float bv = b1[g * 128 + j];
        f32x4 vv = {bv, bv, bv, bv};
        #pragma unroll
        for (int mt = 0; mt < 4; ++mt) acc[mt][g] = vv;
    }

    STAGE1(0, 0);
    short8 bn[4];
    #pragma unroll
    for (int g = 0; g < 4; ++g)
        bn[g] = *(const short8*)(W1F + ((size_t)((g * 8 + w) * 8) * 64 + l) * 8);
    #pragma unroll
    for (int c = 0; c < 8; ++c) {
        __syncthreads();
        short8 bc[4];
        #pragma unroll
        for (int g = 0; g < 4; ++g) bc[g] = bn[g];
        if (c < 7) {
            STAGE1(c + 1, (c + 1) & 1);
            #pragma unroll
            for (int g = 0; g < 4; ++g)
                bn[g] = *(const short8*)(W1F + ((size_t)((g * 8 + w) * 8 + c + 1) * 64 + l) * 8);
        }
        short8 a[4];
        #pragma unroll
        for (int mt = 0; mt < 4; ++mt)
            a[mt] = *(const short8*)(Ab + a_off(c & 1, mt * 16 + lr, lg * 16));
        #pragma unroll
        for (int mt = 0; mt < 4; ++mt)
            #pragma unroll
            for (int g = 0; g < 4; ++g)
                acc[mt][g] = __builtin_amdgcn_mfma_f32_16x16x32_bf16(
                    a[mt], bc[g], acc[mt][g], 0, 0, 0);
    }

    // ---- stage dec-weight SECOND halves into Ab (buf0 safe, see gemm0) ----
    float* dw = (float*)Ab;   // [0..511]=rW rows 256..511, [512..1023]=bW rows 256..511
    if (t < 128)      ((float4*)dw)[t] = ((const float4*)(rW + 512))[t];
    else if (t < 256) ((float4*)dw)[t] = ((const float4*)(bW + 512))[t - 128];

    // ---- epilogue: LSTM cell 1 -> Cs ----
    #pragma unroll
    for (int mt = 0; mt < 4; ++mt) {
        #pragma unroll
        for (int rr = 0; rr < 4; ++rr) {
            const int row  = mt * 16 + lg * 4 + rr;
            const int grow = row0 + row;
            const int n    = grow & (Nc - 1);
            float cold = c1_in[(size_t)grow * Hc + j];
            float ig = sigf(acc[mt][0][rr]);
            float fg = sigf(acc[mt][1][rr]);
            float gv = tanh_(acc[mt][2][rr]);
            float og = sigf(acc[mt][3][rr]);
            float cn = fg * cold + ig * gv;
            float hn = og * tanh_(cn);
            const bool keep = (n == eb) || (n == rbn);
            float cw = keep ? cold : cn;
            float hw = hn;
            if (keep) hw = h1_in[(size_t)grow * Hc + j];   // rare
            *(unsigned short*)(Cs + cs_off(row, j >> 3) + (j & 7) * 2)        = bfu(cw);
            *(unsigned short*)(Cs + cs_off(row, 16 + (j >> 3)) + (j & 7) * 2) = bfu(hw);
        }
    }
    __syncthreads();   // Cs + dw ready
    // Cs -> contrib cols 256..511 (coalesced)
    #pragma unroll
    for (int i = 0; i < 4; ++i) {
        const int idx = i * 512 + t;
        const int r = idx >> 5, u = idx & 31;
        short8 v = *(const short8*)(Cs + cs_off(r, u));
        *(short8*)(contrib + (size_t)(row0 + r) * H4c + 256 + u * 8) = v;
    }

    // ---- dec head second half (cols 256..511, LDS-only) + combine ----
    {
        const int r8 = l >> 3, s = l & 7;
        const int row  = w * 8 + r8;
        const int grow = row0 + row;
        float pr0 = 0.f, pr1 = 0.f, pb0 = 0.f, pb1 = 0.f;
        if (s >= 4) {
            #pragma unroll
            for (int cu = 0; cu < 8; ++cu) {
                short8 ev = *(const short8*)(Cs + cs_off(row, (s - 4) * 8 + cu));
                const int lcol = (s - 4) * 64 + cu * 8;   // 0..255 local
                const float4* rp = (const float4*)(dw + lcol * 2);
                const float4* bp = (const float4*)(dw + 512 + lcol * 2);
                #pragma unroll
                for (int q = 0; q < 4; ++q) {
                    float4 rv = rp[q], bv = bp[q];
                    float e0 = bf2f((unsigned short)ev[q * 2]);
                    float e1 = bf2f((unsigned short)ev[q * 2 + 1]);
                    pr0 += e0 * rv.x + e1 * rv.z;
                    pr1 += e0 * rv.y + e1 * rv.w;
                    pb0 += e0 * bv.x + e1 * bv.z;
                    pb1 += e0 * bv.y + e1 * bv.w;
                }
            }
        }
        #pragma unroll
        for (int m = 1; m < 8; m <<= 1) {
            pr0 += __shfl_xor(pr0, m);
            pr1 += __shfl_xor(pr1, m);
            pb0 += __shfl_xor(pb0, m);
            pb1 += __shfl_xor(pb1, m);
        }
        if (s == 0) {
            float4 wp = w_part[grow];
            pr0 += wp.x; pr1 += wp.y; pb0 += wp.z; pb1 += wp.w;
            const int n = grow & (Nc - 1);
            float r0v = pr0 + rbv[0], r1v = pr1 + rbv[1];
            float m  = fmaxf(r0v, r1v);
            float z0 = __expf(r0v - m), z1 = __expf(r1v - m);
            float inv = 1.f / (z0 + z1);
            float praise = z0 * inv, pno = z1 * inv;
            if (n == eb) { praise = 0.f; pno = 1.f; }
            float q0 = pb0 + bbv[0], q1 = pb1 + bbv[1];
            float mm = fmaxf(q0, q1);
            float y0 = __expf(q0 - mm), y1 = __expf(q1 - mm);
            float binv = 1.f / (y0 + y1);
            float ipv = ip_in[grow];
            w_all[grow]            = praise * ipv;
            w_all[BNc + grow]      = pno * y0 * binv * ipv;
            w_all[2 * BNc + grow]  = pno * y1 * binv * ipv;
        }
    }
#undef STAGE1
}

// ---------------------------------------------------------------------------
// Invert the scatter into per-target linked lists. e = row*4 + type.
// ---------------------------------------------------------------------------
__global__ __launch_bounds__(256) void build_kernel(
    const int* __restrict__ t_idx, const int* __restrict__ f_idx,
    const int* __restrict__ r_idx, int* __restrict__ head, int* __restrict__ nxt)
{
    const int row  = blockIdx.x * 256 + threadIdx.x;
    const int base = (row >> 11) << 11;
    const int e0 = row * 4;
    int o;
    o = atomicExch(&head[base + r_idx[row]], e0);     nxt[e0]     = o;
    o = atomicExch(&head[base + t_idx[row]], e0 + 1); nxt[e0 + 1] = o;
    o = atomicExch(&head[base + f_idx[row]], e0 + 2); nxt[e0 + 2] = o;
}

// ---------------------------------------------------------------------------
// Gather: one wave per target (b,m). Dword (2 x bf16) loads per lane.
// ---------------------------------------------------------------------------
__global__ __launch_bounds__(256) void gather_kernel(
    const unsigned short* __restrict__ contrib, const float* __restrict__ w_all,
    const int* __restrict__ head, const int* __restrict__ nxt,
    const float* __restrict__ c0_in, const float* __restrict__ h0_in,
    const float* __restrict__ c1_in, const float* __restrict__ h1_in,
    const float* __restrict__ ip_in,
    const int* __restrict__ cstep, const int* __restrict__ slim,
    float* __restrict__ out)
{
    const int gtid = blockIdx.x * 256 + threadIdx.x;
    const int wid  = gtid >> 6;
    const int l    = gtid & 63;
    const int bidx = wid >> 11;

    float ax[4] = {0.f, 0.f, 0.f, 0.f};
    float ay[4] = {0.f, 0.f, 0.f, 0.f};
    float ipsum = 0.f;

    int e = head[wid];
    while (e >= 0) {
        const int src = e >> 2;
        const float w = w_all[(e & 3) * BNc + src];
        const unsigned* crow = (const unsigned*)(contrib + (size_t)src * 512);
        #pragma unroll
        for (int q = 0; q < 4; ++q) {
            unsigned pv = crow[q * 64 + l];   // elements q*128+2l, q*128+2l+1
            ax[q] += w * bf2f((unsigned short)(pv & 0xFFFFu));
            ay[q] += w * bf2f((unsigned short)(pv >> 16));
        }
        ipsum += w;
        e = nxt[e];
    }

    const bool live = cstep[bidx] < slim[bidx];
    float* orow = out + (size_t)wid * 513;
    if (live) {
        const float inv = 1.f / (ipsum + 1e-7f);
        #pragma unroll
        for (int q = 0; q < 4; ++q) {
            const int idx0 = q * 128 + 2 * l;
            orow[idx0]     = ax[q] * inv;
            orow[idx0 + 1] = ay[q] * inv;
        }
        if (l == 0) orow[512] = ipsum;
    } else {
        #pragma unroll
        for (int q = 0; q < 4; ++q) {
            const float* p = q == 0 ? c0_in : q == 1 ? h0_in
                           : q == 2 ? c1_in : h1_in;
            float2 v = *(const float2*)(p + (size_t)wid * Hc + 2 * l);
            const int idx0 = q * 128 + 2 * l;
            orow[idx0]     = v.x;
            orow[idx0 + 1] = v.y;
        }
        if (l == 0) orow[512] = ip_in[wid];
    }
}

extern "C" void kernel_launch(void* const* d_in, const int* in_sizes, int n_in,
                              void* d_out, int out_size, void* d_ws, size_t ws_size,
                              hipStream_t stream) {
    const float* x     = (const float*)d_in[0];
    const float* c0    = (const float*)d_in[1];
    const float* h0    = (const float*)d_in[2];
    const float* c1    = (const float*)d_in[3];
    const float* h1    = (const float*)d_in[4];
    const float* ip    = (const float*)d_in[5];
    const float* Wx0   = (const float*)d_in[6];
    const float* Wh0   = (const float*)d_in[7];
    const float* b0    = (const float*)d_in[8];
    const float* Wx1   = (const float*)d_in[9];
    const float* Wh1   = (const float*)d_in[10];
    const float* b1    = (const float*)d_in[11];
    const float* rW    = (const float*)d_in[12];
    const float* rb    = (const float*)d_in[13];
    const float* bW    = (const float*)d_in[14];
    const float* bb    = (const float*)d_in[15];
    const int* t_idx   = (const int*)d_in[16];
    const int* f_idx   = (const int*)d_in[17];
    const int* r_idx   = (const int*)d_in[18];
    const int* exit_i  = (const int*)d_in[19];
    const int* raise_i = (const int*)d_in[20];
    const int* cstep   = (const int*)d_in[21];
    const int* slim    = (const int*)d_in[22];
    float* out = (float*)d_out;

    // workspace layout
    unsigned short* contrib = (unsigned short*)d_ws;            // BN*512 bf16 (64 MiB)
    unsigned short* W0F = contrib + (size_t)BNc * 512;          // 512*256 bf16
    unsigned short* W1F = W0F + 512 * 256;
    float* w_all = (float*)(W1F + 512 * 256);                   // 3*BN f32
    int*   head  = (int*)(w_all + 3 * (size_t)BNc);             // BN int
    int*   nxt   = head + BNc;                                  // 4*BN int
    float4* w_part = (float4*)(nxt + 4 * (size_t)BNc);          // BN float4 (1 MiB)

    prep_kernel<<<64, 256, 0, stream>>>(Wx0, Wh0, Wx1, Wh1, W0F, W1F, head);
    build_kernel<<<BNc / 256, 256, 0, stream>>>(t_idx, f_idx, r_idx, head, nxt);
    gemm0_kernel<<<BNc / 64, 512, 0, stream>>>(x, c0, h0, W0F, b0, rW, bW,
                                               exit_i, raise_i, contrib, w_part);
    gemm1_kernel<<<BNc / 64, 512, 0, stream>>>(contrib, c1, h1, W1F, b1,
                                               rW, rb, bW, bb, ip, w_part,
                                               exit_i, raise_i, contrib, w_all);
    gather_kernel<<<BNc / 4, 256, 0, stream>>>(contrib, w_all, head, nxt,
                                               c0, h0, c1, h1, ip, cstep, slim, out);
}

// Round 17
// 197.908 us; speedup vs baseline: 1.0855x; 1.0855x over previous
//
#include <hip/hip_runtime.h>
#include <hip/hip_bf16.h>

// Problem constants (match reference setup_inputs)
constexpr int Bc  = 32;
constexpr int Nc  = 2048;
constexpr int Hc  = 128;
constexpr int H4c = 512;
constexpr int BNc = Bc * Nc;   // 65536 rows

typedef __attribute__((ext_vector_type(8))) short short8;
typedef __attribute__((ext_vector_type(4))) float f32x4;

// clamp-free: v_exp saturates to 0/inf, forms below stay finite/correct
__device__ __forceinline__ float sigf(float x)  { return 1.f / (1.f + __expf(-x)); }
__device__ __forceinline__ float tanh_(float x) { return 1.f - 2.f / (__expf(2.f * x) + 1.f); }

// f32 -> bf16 bits (RNE)
__device__ __forceinline__ unsigned short bfu(float f) {
    union { float f; unsigned u; } a; a.f = f;
    unsigned u = a.u;
    return (unsigned short)((u + 0x7FFFu + ((u >> 16) & 1u)) >> 16);
}
__device__ __forceinline__ float bf2f(unsigned short u) {
    union { unsigned u; float f; } a; a.u = ((unsigned)u) << 16;
    return a.f;
}
// HW packed conversion: lo -> bits[15:0], hi -> bits[31:16], RNE
__device__ __forceinline__ unsigned cvtpk(float lo, float hi) {
    unsigned r;
    asm("v_cvt_pk_bf16_f32 %0, %1, %2" : "=v"(r) : "v"(lo), "v"(hi));
    return r;
}

// A-tile (dbuf staging): row stride 80 B (64 B data + 16 pad).
__device__ __forceinline__ int a_off(int buf, int row, int byte) {
    return buf * 5120 + row * 80 + byte;
}
// Cs tile: 64 rows x 32 units of 16 B, XOR swizzle.
__device__ __forceinline__ int cs_off(int row, int unit) {
    return row * 512 + ((unit ^ (row & 7)) << 4);
}

// ---------------------------------------------------------------------------
// Weight prep -> fragment-major: WF[ct][ks][lane][e], col = ct*16 + (lane&15),
// k = ks*32 + (lane>>4)*8 + e. Also clears head[] (-1), replacing the
// separate memset dispatch.
// ---------------------------------------------------------------------------
__global__ __launch_bounds__(256) void prep_kernel(
    const float* __restrict__ Wx0, const float* __restrict__ Wh0,
    const float* __restrict__ Wx1, const float* __restrict__ Wh1,
    unsigned short* __restrict__ W0F, unsigned short* __restrict__ W1F,
    int* __restrict__ head)
{
    int idx = blockIdx.x * 256 + threadIdx.x;   // 0..16383 = (ct,ks,lane)
    int4 m1 = { -1, -1, -1, -1 };
    ((int4*)head)[idx] = m1;                    // 16384 x int4 = 65536 ints

    int ct = idx >> 9, ks = (idx >> 6) & 7, lane = idx & 63;
    int col = ct * 16 + (lane & 15);
    unsigned short* p0 = W0F + (size_t)idx * 8;
    unsigned short* p1 = W1F + (size_t)idx * 8;
    #pragma unroll
    for (int e = 0; e < 8; ++e) {
        int k = ks * 32 + (lane >> 4) * 8 + e;
        float v0 = (k < 128) ? Wx0[k * 512 + col] : Wh0[(k - 128) * 512 + col];
        float v1 = (k < 128) ? Wx1[k * 512 + col] : Wh1[(k - 128) * 512 + col];
        p0[e] = bfu(v0);
        p1[e] = bfu(v1);
    }
}

// ---------------------------------------------------------------------------
// gemm0: 512 thr / 8 waves / 64 rows x all 512 cols — champion structure.
// Chunked dbuf A staging ([x|h0] f32 -> bf16), B register-prefetched from L2
// fragment-major, one barrier per chunk. Epilogue: LSTM cell 0 -> Cs ->
// contrib[:,0:256]. NO A1 tensor (gemm1 reads masked h0n from contrib).
// ---------------------------------------------------------------------------
__global__ __launch_bounds__(512, 4) void gemm0_kernel(
    const float* __restrict__ x_in,  const float* __restrict__ c0_in,
    const float* __restrict__ h0_in,
    const unsigned short* __restrict__ W0F, const float* __restrict__ b0,
    const int* __restrict__ exit_i, const int* __restrict__ raise_i,
    unsigned short* __restrict__ contrib)
{
    __shared__ __align__(16) char Ab[10240];   // A dbuf, 2 x 64 rows x 80 B
    __shared__ __align__(16) char Cs[32768];   // 64 rows x 256 bf16 restage

    const int t    = threadIdx.x;
    const int w    = t >> 6, l = t & 63, lr = l & 15, lg = l >> 4;
    const int row0 = blockIdx.x * 64;
    const int bidx = row0 >> 11;
    const int eb   = exit_i[bidx];
    const int rbn  = raise_i[bidx];
    const int j    = w * 16 + lr;

    const int srow = t >> 3, sfq = t & 7;
#define STAGE0(c, bi)                                                          \
    {                                                                          \
        const float* sp = ((c) < 4 ? x_in : h0_in)                             \
            + (size_t)(row0 + srow) * Hc + ((c) & 3) * 32 + sfq * 4;           \
        float4 v = *(const float4*)sp;                                         \
        uint2 b2 = { cvtpk(v.x, v.y), cvtpk(v.z, v.w) };                       \
        *(uint2*)(Ab + a_off(bi, srow, sfq * 8)) = b2;                         \
    }

    f32x4 acc[4][4];
    #pragma unroll
    for (int g = 0; g < 4; ++g) {
        float bv = b0[g * 128 + j];
        f32x4 vv = {bv, bv, bv, bv};
        #pragma unroll
        for (int mt = 0; mt < 4; ++mt) acc[mt][g] = vv;
    }

    STAGE0(0, 0);
    short8 bn[4];
    #pragma unroll
    for (int g = 0; g < 4; ++g)
        bn[g] = *(const short8*)(W0F + ((size_t)((g * 8 + w) * 8) * 64 + l) * 8);
    #pragma unroll
    for (int c = 0; c < 8; ++c) {
        __syncthreads();
        short8 bc[4];
        #pragma unroll
        for (int g = 0; g < 4; ++g) bc[g] = bn[g];
        if (c < 7) {
            STAGE0(c + 1, (c + 1) & 1);
            #pragma unroll
            for (int g = 0; g < 4; ++g)
                bn[g] = *(const short8*)(W0F + ((size_t)((g * 8 + w) * 8 + c + 1) * 64 + l) * 8);
        }
        short8 a[4];
        #pragma unroll
        for (int mt = 0; mt < 4; ++mt)
            a[mt] = *(const short8*)(Ab + a_off(c & 1, mt * 16 + lr, lg * 16));
        #pragma unroll
        for (int mt = 0; mt < 4; ++mt)
            #pragma unroll
            for (int g = 0; g < 4; ++g)
                acc[mt][g] = __builtin_amdgcn_mfma_f32_16x16x32_bf16(
                    a[mt], bc[g], acc[mt][g], 0, 0, 0);
    }

    // ---- epilogue: LSTM cell 0 -> Cs (inline loads, no arrays) ----
    #pragma unroll
    for (int mt = 0; mt < 4; ++mt) {
        #pragma unroll
        for (int rr = 0; rr < 4; ++rr) {
            const int row  = mt * 16 + lg * 4 + rr;
            const int grow = row0 + row;
            const int n    = grow & (Nc - 1);
            float cold = c0_in[(size_t)grow * Hc + j];
            float ig = sigf(acc[mt][0][rr]);
            float fg = sigf(acc[mt][1][rr]);
            float gv = tanh_(acc[mt][2][rr]);
            float og = sigf(acc[mt][3][rr]);
            float cn = fg * cold + ig * gv;
            float hn = og * tanh_(cn);
            const bool keep = (n == eb) || (n == rbn);
            float cw = keep ? cold : cn;
            float hw = hn;
            if (keep) hw = h0_in[(size_t)grow * Hc + j];   // rare (2 rows/batch)
            *(unsigned short*)(Cs + cs_off(row, j >> 3) + (j & 7) * 2)        = bfu(cw);
            *(unsigned short*)(Cs + cs_off(row, 16 + (j >> 3)) + (j & 7) * 2) = bfu(hw);
        }
    }
    __syncthreads();
    // Cs -> contrib cols 0..255 (coalesced 16B stores)
    #pragma unroll
    for (int i = 0; i < 4; ++i) {
        const int idx = i * 512 + t;
        const int r = idx >> 5, u = idx & 31;
        short8 v = *(const short8*)(Cs + cs_off(r, u));
        *(short8*)(contrib + (size_t)(row0 + r) * H4c + u * 8) = v;
    }
#undef STAGE0
}

// ---------------------------------------------------------------------------
// gemm1: A = [h0n (bf16 from contrib cols 128..255) | h1 (f32->bf16)] via
// chunked dbuf staging. Epilogue: LSTM cell 1 -> contrib[:,256:512] +
// fused decision head.
// ---------------------------------------------------------------------------
__global__ __launch_bounds__(512, 4) void gemm1_kernel(
    const unsigned short* __restrict__ contrib_r, const float* __restrict__ c1_in,
    const float* __restrict__ h1_in,
    const unsigned short* __restrict__ W1F, const float* __restrict__ b1,
    const float* __restrict__ rW, const float* __restrict__ rbv,
    const float* __restrict__ bW, const float* __restrict__ bbv,
    const float* __restrict__ ip_in,
    const int* __restrict__ exit_i, const int* __restrict__ raise_i,
    unsigned short* __restrict__ contrib, float* __restrict__ w_all)
{
    __shared__ __align__(16) char Ab[10240];   // A dbuf; later dec weights
    __shared__ __align__(16) char Cs[32768];   // 64 rows x 256 bf16 restage

    const int t    = threadIdx.x;
    const int w    = t >> 6, l = t & 63, lr = l & 15, lg = l >> 4;
    const int row0 = blockIdx.x * 64;
    const int bidx = row0 >> 11;
    const int eb   = exit_i[bidx];
    const int rbn  = raise_i[bidx];
    const int j    = w * 16 + lr;

    const int srow = t >> 3, sfq = t & 7;
    // chunk c: c<4 -> h0n bf16 from contrib cols 128+c*32.. ; c>=4 -> h1 f32
#define STAGE1(c, bi)                                                          \
    {                                                                          \
        if ((c) < 4) {                                                         \
            ushort4 v = *(const ushort4*)(contrib_r                            \
                + (size_t)(row0 + srow) * H4c + 128 + ((c) & 3) * 32 + sfq * 4); \
            *(ushort4*)(Ab + a_off(bi, srow, sfq * 8)) = v;                    \
        } else {                                                               \
            const float* sp = h1_in + (size_t)(row0 + srow) * Hc               \
                + ((c) & 3) * 32 + sfq * 4;                                    \
            float4 v = *(const float4*)sp;                                     \
            uint2 b2 = { cvtpk(v.x, v.y), cvtpk(v.z, v.w) };                   \
            *(uint2*)(Ab + a_off(bi, srow, sfq * 8)) = b2;                     \
        }                                                                      \
    }

    f32x4 acc[4][4];
    #pragma unroll
    for (int g = 0; g < 4; ++g) {
        float bv = b1[g * 128 + j];
        f32x4 vv = {bv, bv, bv, bv};
        #pragma unroll
        for (int mt = 0; mt < 4; ++mt) acc[mt][g] = vv;
    }

    STAGE1(0, 0);
    short8 bn[4];
    #pragma unroll
    for (int g = 0; g < 4; ++g)
        bn[g] = *(const short8*)(W1F + ((size_t)((g * 8 + w) * 8) * 64 + l) * 8);
    #pragma unroll
    for (int c = 0; c < 8; ++c) {
        __syncthreads();
        short8 bc[4];
        #pragma unroll
        for (int g = 0; g < 4; ++g) bc[g] = bn[g];
        if (c < 7) {
            STAGE1(c + 1, (c + 1) & 1);
            #pragma unroll
            for (int g = 0; g < 4; ++g)
                bn[g] = *(const short8*)(W1F + ((size_t)((g * 8 + w) * 8 + c + 1) * 64 + l) * 8);
        }
        short8 a[4];
        #pragma unroll
        for (int mt = 0; mt < 4; ++mt)
            a[mt] = *(const short8*)(Ab + a_off(c & 1, mt * 16 + lr, lg * 16));
        #pragma unroll
        for (int mt = 0; mt < 4; ++mt)
            #pragma unroll
            for (int g = 0; g < 4; ++g)
                acc[mt][g] = __builtin_amdgcn_mfma_f32_16x16x32_bf16(
                    a[mt], bc[g], acc[mt][g], 0, 0, 0);
    }

    // ---- epilogue: LSTM cell 1 -> Cs ----
    #pragma unroll
    for (int mt = 0; mt < 4; ++mt) {
        #pragma unroll
        for (int rr = 0; rr < 4; ++rr) {
            const int row  = mt * 16 + lg * 4 + rr;
            const int grow = row0 + row;
            const int n    = grow & (Nc - 1);
            float cold = c1_in[(size_t)grow * Hc + j];
            float ig = sigf(acc[mt][0][rr]);
            float fg = sigf(acc[mt][1][rr]);
            float gv = tanh_(acc[mt][2][rr]);
            float og = sigf(acc[mt][3][rr]);
            float cn = fg * cold + ig * gv;
            float hn = og * tanh_(cn);
            const bool keep = (n == eb) || (n == rbn);
            float cw = keep ? cold : cn;
            float hw = hn;
            if (keep) hw = h1_in[(size_t)grow * Hc + j];   // rare
            *(unsigned short*)(Cs + cs_off(row, j >> 3) + (j & 7) * 2)        = bfu(cw);
            *(unsigned short*)(Cs + cs_off(row, 16 + (j >> 3)) + (j & 7) * 2) = bfu(hw);
        }
    }
    __syncthreads();   // all Ab reads done; Cs filled
    // stage dec weights into Ab (f32): dw[0..1023]=rW, dw[1024..2047]=bW
    float* dw = (float*)Ab;
    if (t < 256) {
        ((float4*)dw)[t]       = ((const float4*)rW)[t];
        ((float4*)dw)[256 + t] = ((const float4*)bW)[t];
    }
    __syncthreads();
    // Cs -> contrib cols 256..511 (coalesced)
    #pragma unroll
    for (int i = 0; i < 4; ++i) {
        const int idx = i * 512 + t;
        const int r = idx >> 5, u = idx & 31;
        short8 v = *(const short8*)(Cs + cs_off(r, u));
        *(short8*)(contrib + (size_t)(row0 + r) * H4c + 256 + u * 8) = v;
    }

    // ---- fused decision head: wave w -> rows w*8..w*8+7, 8 lanes per row ----
    {
        const int r8 = l >> 3, s = l & 7;     // row-in-wave, 64-col slice
        const int row  = w * 8 + r8;
        const int grow = row0 + row;
        float pr0 = 0.f, pr1 = 0.f, pb0 = 0.f, pb1 = 0.f;
        #pragma unroll
        for (int cu = 0; cu < 8; ++cu) {
            short8 ev;
            if (s < 4)   // comps 0,1 from global contrib (gemm0, L3-hot)
                ev = *(const short8*)(contrib_r + (size_t)grow * H4c + s * 64 + cu * 8);
            else         // comps 2,3 from Cs
                ev = *(const short8*)(Cs + cs_off(row, (s - 4) * 8 + cu));
            const int col0 = s * 64 + cu * 8;
            const float4* rp = (const float4*)(dw + col0 * 2);
            const float4* bp = (const float4*)(dw + 1024 + col0 * 2);
            #pragma unroll
            for (int q = 0; q < 4; ++q) {
                float4 rv = rp[q], bv = bp[q];
                float e0 = bf2f((unsigned short)ev[q * 2]);
                float e1 = bf2f((unsigned short)ev[q * 2 + 1]);
                pr0 += e0 * rv.x + e1 * rv.z;
                pr1 += e0 * rv.y + e1 * rv.w;
                pb0 += e0 * bv.x + e1 * bv.z;
                pb1 += e0 * bv.y + e1 * bv.w;
            }
        }
        #pragma unroll
        for (int m = 1; m < 8; m <<= 1) {
            pr0 += __shfl_xor(pr0, m);
            pr1 += __shfl_xor(pr1, m);
            pb0 += __shfl_xor(pb0, m);
            pb1 += __shfl_xor(pb1, m);
        }
        if (s == 0) {
            const int n = grow & (Nc - 1);
            float r0v = pr0 + rbv[0], r1v = pr1 + rbv[1];
            float m  = fmaxf(r0v, r1v);
            float z0 = __expf(r0v - m), z1 = __expf(r1v - m);
            float inv = 1.f / (z0 + z1);
            float praise = z0 * inv, pno = z1 * inv;
            if (n == eb) { praise = 0.f; pno = 1.f; }
            float q0 = pb0 + bbv[0], q1 = pb1 + bbv[1];
            float mm = fmaxf(q0, q1);
            float y0 = __expf(q0 - mm), y1 = __expf(q1 - mm);
            float binv = 1.f / (y0 + y1);
            float ipv = ip_in[grow];
            w_all[grow]            = praise * ipv;
            w_all[BNc + grow]      = pno * y0 * binv * ipv;
            w_all[2 * BNc + grow]  = pno * y1 * binv * ipv;
        }
    }
#undef STAGE1
}

// ---------------------------------------------------------------------------
// Invert the scatter into per-target linked lists. e = row*4 + type.
// ---------------------------------------------------------------------------
__global__ __launch_bounds__(256) void build_kernel(
    const int* __restrict__ t_idx, const int* __restrict__ f_idx,
    const int* __restrict__ r_idx, int* __restrict__ head, int* __restrict__ nxt)
{
    const int row  = blockIdx.x * 256 + threadIdx.x;
    const int base = (row >> 11) << 11;
    const int e0 = row * 4;
    int o;
    o = atomicExch(&head[base + r_idx[row]], e0);     nxt[e0]     = o;
    o = atomicExch(&head[base + t_idx[row]], e0 + 1); nxt[e0 + 1] = o;
    o = atomicExch(&head[base + f_idx[row]], e0 + 2); nxt[e0 + 2] = o;
}

// ---------------------------------------------------------------------------
// Gather: one wave per target (b,m). Dword (2 x bf16) loads per lane —
// lane l handles elements q*128 + 2l, 2l+1 (q = comp index 0..3).
// ---------------------------------------------------------------------------
__global__ __launch_bounds__(256) void gather_kernel(
    const unsigned short* __restrict__ contrib, const float* __restrict__ w_all,
    const int* __restrict__ head, const int* __restrict__ nxt,
    const float* __restrict__ c0_in, const float* __restrict__ h0_in,
    const float* __restrict__ c1_in, const float* __restrict__ h1_in,
    const float* __restrict__ ip_in,
    const int* __restrict__ cstep, const int* __restrict__ slim,
    float* __restrict__ out)
{
    const int gtid = blockIdx.x * 256 + threadIdx.x;
    const int wid  = gtid >> 6;
    const int l    = gtid & 63;
    const int bidx = wid >> 11;

    float ax[4] = {0.f, 0.f, 0.f, 0.f};
    float ay[4] = {0.f, 0.f, 0.f, 0.f};
    float ipsum = 0.f;

    int e = head[wid];
    while (e >= 0) {
        const int src = e >> 2;
        const float w = w_all[(e & 3) * BNc + src];
        const unsigned* crow = (const unsigned*)(contrib + (size_t)src * 512);
        #pragma unroll
        for (int q = 0; q < 4; ++q) {
            unsigned pv = crow[q * 64 + l];   // elements q*128+2l, q*128+2l+1
            ax[q] += w * bf2f((unsigned short)(pv & 0xFFFFu));
            ay[q] += w * bf2f((unsigned short)(pv >> 16));
        }
        ipsum += w;
        e = nxt[e];
    }

    const bool live = cstep[bidx] < slim[bidx];
    float* orow = out + (size_t)wid * 513;
    if (live) {
        const float inv = 1.f / (ipsum + 1e-7f);
        #pragma unroll
        for (int q = 0; q < 4; ++q) {
            const int idx0 = q * 128 + 2 * l;
            orow[idx0]     = ax[q] * inv;
            orow[idx0 + 1] = ay[q] * inv;
        }
        if (l == 0) orow[512] = ipsum;
    } else {
        #pragma unroll
        for (int q = 0; q < 4; ++q) {
            const float* p = q == 0 ? c0_in : q == 1 ? h0_in
                           : q == 2 ? c1_in : h1_in;
            float2 v = *(const float2*)(p + (size_t)wid * Hc + 2 * l);
            const int idx0 = q * 128 + 2 * l;
            orow[idx0]     = v.x;
            orow[idx0 + 1] = v.y;
        }
        if (l == 0) orow[512] = ip_in[wid];
    }
}

extern "C" void kernel_launch(void* const* d_in, const int* in_sizes, int n_in,
                              void* d_out, int out_size, void* d_ws, size_t ws_size,
                              hipStream_t stream) {
    const float* x     = (const float*)d_in[0];
    const float* c0    = (const float*)d_in[1];
    const float* h0    = (const float*)d_in[2];
    const float* c1    = (const float*)d_in[3];
    const float* h1    = (const float*)d_in[4];
    const float* ip    = (const float*)d_in[5];
    const float* Wx0   = (const float*)d_in[6];
    const float* Wh0   = (const float*)d_in[7];
    const float* b0    = (const float*)d_in[8];
    const float* Wx1   = (const float*)d_in[9];
    const float* Wh1   = (const float*)d_in[10];
    const float* b1    = (const float*)d_in[11];
    const float* rW    = (const float*)d_in[12];
    const float* rb    = (const float*)d_in[13];
    const float* bW    = (const float*)d_in[14];
    const float* bb    = (const float*)d_in[15];
    const int* t_idx   = (const int*)d_in[16];
    const int* f_idx   = (const int*)d_in[17];
    const int* r_idx   = (const int*)d_in[18];
    const int* exit_i  = (const int*)d_in[19];
    const int* raise_i = (const int*)d_in[20];
    const int* cstep   = (const int*)d_in[21];
    const int* slim    = (const int*)d_in[22];
    float* out = (float*)d_out;

    // workspace layout (no A1)
    unsigned short* contrib = (unsigned short*)d_ws;            // BN*512 bf16 (64 MiB)
    unsigned short* W0F = contrib + (size_t)BNc * 512;          // 512*256 bf16
    unsigned short* W1F = W0F + 512 * 256;
    float* w_all = (float*)(W1F + 512 * 256);                   // 3*BN f32
    int*   head  = (int*)(w_all + 3 * (size_t)BNc);             // BN int
    int*   nxt   = head + BNc;                                  // 4*BN int

    prep_kernel<<<64, 256, 0, stream>>>(Wx0, Wh0, Wx1, Wh1, W0F, W1F, head);
    build_kernel<<<BNc / 256, 256, 0, stream>>>(t_idx, f_idx, r_idx, head, nxt);
    gemm0_kernel<<<BNc / 64, 512, 0, stream>>>(x, c0, h0, W0F, b0,
                                               exit_i, raise_i, contrib);
    gemm1_kernel<<<BNc / 64, 512, 0, stream>>>(contrib, c1, h1, W1F, b1,
                                               rW, rb, bW, bb, ip,
                                               exit_i, raise_i, contrib, w_all);
    gather_kernel<<<BNc / 4, 256, 0, stream>>>(contrib, w_all, head, nxt,
                                               c0, h0, c1, h1, ip, cstep, slim, out);
}

// Round 18
// 184.602 us; speedup vs baseline: 1.1637x; 1.0721x over previous
//
#include <hip/hip_runtime.h>
#include <hip/hip_bf16.h>

// Problem constants (match reference setup_inputs)
constexpr int Bc  = 32;
constexpr int Nc  = 2048;
constexpr int Hc  = 128;
constexpr int H4c = 512;
constexpr int BNc = Bc * Nc;   // 65536 rows

typedef __attribute__((ext_vector_type(8))) short short8;
typedef __attribute__((ext_vector_type(4))) float f32x4;

// clamp-free: v_exp saturates to 0/inf, forms below stay finite/correct
__device__ __forceinline__ float sigf(float x)  { return 1.f / (1.f + __expf(-x)); }
__device__ __forceinline__ float tanh_(float x) { return 1.f - 2.f / (__expf(2.f * x) + 1.f); }

// f32 -> bf16 bits (RNE)
__device__ __forceinline__ unsigned short bfu(float f) {
    union { float f; unsigned u; } a; a.f = f;
    unsigned u = a.u;
    return (unsigned short)((u + 0x7FFFu + ((u >> 16) & 1u)) >> 16);
}
__device__ __forceinline__ float bf2f(unsigned short u) {
    union { unsigned u; float f; } a; a.u = ((unsigned)u) << 16;
    return a.f;
}
// HW packed conversion: lo -> bits[15:0], hi -> bits[31:16], RNE
__device__ __forceinline__ unsigned cvtpk(float lo, float hi) {
    unsigned r;
    asm("v_cvt_pk_bf16_f32 %0, %1, %2" : "=v"(r) : "v"(lo), "v"(hi));
    return r;
}

// A-tile (dbuf staging): row stride 80 B (64 B data + 16 pad).
__device__ __forceinline__ int a_off(int buf, int row, int byte) {
    return buf * 5120 + row * 80 + byte;
}
// Cs tile: 64 rows x 32 units of 16 B, XOR swizzle.
__device__ __forceinline__ int cs_off(int row, int unit) {
    return row * 512 + ((unit ^ (row & 7)) << 4);
}

// ---------------------------------------------------------------------------
// Weight prep -> fragment-major: WF[ct][ks][lane][e], col = ct*16 + (lane&15),
// k = ks*32 + (lane>>4)*8 + e. Also clears head[] (-1) and builds the
// decision-head B-operand DF[16 ks][64 lanes][8] bf16 where logical col
// (lane&15): 0=rW[:,0], 1=rW[:,1], 2=bW[:,0], 3=bW[:,1], 4..15 = 0.
// ---------------------------------------------------------------------------
__global__ __launch_bounds__(256) void prep_kernel(
    const float* __restrict__ Wx0, const float* __restrict__ Wh0,
    const float* __restrict__ Wx1, const float* __restrict__ Wh1,
    const float* __restrict__ rW, const float* __restrict__ bW,
    unsigned short* __restrict__ W0F, unsigned short* __restrict__ W1F,
    unsigned short* __restrict__ DF, int* __restrict__ head)
{
    int idx = blockIdx.x * 256 + threadIdx.x;   // 0..16383 = (ct,ks,lane)
    int4 m1 = { -1, -1, -1, -1 };
    ((int4*)head)[idx] = m1;                    // 16384 x int4 = 65536 ints

    int ct = idx >> 9, ks = (idx >> 6) & 7, lane = idx & 63;
    int col = ct * 16 + (lane & 15);
    unsigned short* p0 = W0F + (size_t)idx * 8;
    unsigned short* p1 = W1F + (size_t)idx * 8;
    #pragma unroll
    for (int e = 0; e < 8; ++e) {
        int k = ks * 32 + (lane >> 4) * 8 + e;
        float v0 = (k < 128) ? Wx0[k * 512 + col] : Wh0[(k - 128) * 512 + col];
        float v1 = (k < 128) ? Wx1[k * 512 + col] : Wh1[(k - 128) * 512 + col];
        p0[e] = bfu(v0);
        p1[e] = bfu(v1);
    }

    // DF: 16 ks x 64 lanes (first 1024 global threads)
    if (idx < 1024) {
        int dks = idx >> 6, dl = idx & 63;
        int dcol = dl & 15;
        int kb   = dks * 32 + (dl >> 4) * 8;
        unsigned short* pd = DF + (size_t)idx * 8;
        #pragma unroll
        for (int e = 0; e < 8; ++e) {
            int k = kb + e;
            float v = 0.f;
            if (dcol < 2)      v = rW[k * 2 + dcol];
            else if (dcol < 4) v = bW[k * 2 + (dcol - 2)];
            pd[e] = bfu(v);
        }
    }
}

// ---------------------------------------------------------------------------
// gemm0: 512 thr / 8 waves / 64 rows x all 512 cols — champion structure.
// Chunked dbuf A staging ([x|h0] f32 -> bf16), B register-prefetched from L2
// fragment-major, one barrier per chunk. Epilogue: LSTM cell 0 -> Cs ->
// contrib[:,0:256]. NO A1 tensor (gemm1 reads masked h0n from contrib).
// ---------------------------------------------------------------------------
__global__ __launch_bounds__(512, 4) void gemm0_kernel(
    const float* __restrict__ x_in,  const float* __restrict__ c0_in,
    const float* __restrict__ h0_in,
    const unsigned short* __restrict__ W0F, const float* __restrict__ b0,
    const int* __restrict__ exit_i, const int* __restrict__ raise_i,
    unsigned short* __restrict__ contrib)
{
    __shared__ __align__(16) char Ab[10240];   // A dbuf, 2 x 64 rows x 80 B
    __shared__ __align__(16) char Cs[32768];   // 64 rows x 256 bf16 restage

    const int t    = threadIdx.x;
    const int w    = t >> 6, l = t & 63, lr = l & 15, lg = l >> 4;
    const int row0 = blockIdx.x * 64;
    const int bidx = row0 >> 11;
    const int eb   = exit_i[bidx];
    const int rbn  = raise_i[bidx];
    const int j    = w * 16 + lr;

    const int srow = t >> 3, sfq = t & 7;
#define STAGE0(c, bi)                                                          \
    {                                                                          \
        const float* sp = ((c) < 4 ? x_in : h0_in)                             \
            + (size_t)(row0 + srow) * Hc + ((c) & 3) * 32 + sfq * 4;           \
        float4 v = *(const float4*)sp;                                         \
        uint2 b2 = { cvtpk(v.x, v.y), cvtpk(v.z, v.w) };                       \
        *(uint2*)(Ab + a_off(bi, srow, sfq * 8)) = b2;                         \
    }

    f32x4 acc[4][4];
    #pragma unroll
    for (int g = 0; g < 4; ++g) {
        float bv = b0[g * 128 + j];
        f32x4 vv = {bv, bv, bv, bv};
        #pragma unroll
        for (int mt = 0; mt < 4; ++mt) acc[mt][g] = vv;
    }

    STAGE0(0, 0);
    short8 bn[4];
    #pragma unroll
    for (int g = 0; g < 4; ++g)
        bn[g] = *(const short8*)(W0F + ((size_t)((g * 8 + w) * 8) * 64 + l) * 8);
    #pragma unroll
    for (int c = 0; c < 8; ++c) {
        __syncthreads();
        short8 bc[4];
        #pragma unroll
        for (int g = 0; g < 4; ++g) bc[g] = bn[g];
        if (c < 7) {
            STAGE0(c + 1, (c + 1) & 1);
            #pragma unroll
            for (int g = 0; g < 4; ++g)
                bn[g] = *(const short8*)(W0F + ((size_t)((g * 8 + w) * 8 + c + 1) * 64 + l) * 8);
        }
        short8 a[4];
        #pragma unroll
        for (int mt = 0; mt < 4; ++mt)
            a[mt] = *(const short8*)(Ab + a_off(c & 1, mt * 16 + lr, lg * 16));
        #pragma unroll
        for (int mt = 0; mt < 4; ++mt)
            #pragma unroll
            for (int g = 0; g < 4; ++g)
                acc[mt][g] = __builtin_amdgcn_mfma_f32_16x16x32_bf16(
                    a[mt], bc[g], acc[mt][g], 0, 0, 0);
    }

    // ---- epilogue: LSTM cell 0 -> Cs (inline loads, no arrays) ----
    #pragma unroll
    for (int mt = 0; mt < 4; ++mt) {
        #pragma unroll
        for (int rr = 0; rr < 4; ++rr) {
            const int row  = mt * 16 + lg * 4 + rr;
            const int grow = row0 + row;
            const int n    = grow & (Nc - 1);
            float cold = c0_in[(size_t)grow * Hc + j];
            float ig = sigf(acc[mt][0][rr]);
            float fg = sigf(acc[mt][1][rr]);
            float gv = tanh_(acc[mt][2][rr]);
            float og = sigf(acc[mt][3][rr]);
            float cn = fg * cold + ig * gv;
            float hn = og * tanh_(cn);
            const bool keep = (n == eb) || (n == rbn);
            float cw = keep ? cold : cn;
            float hw = hn;
            if (keep) hw = h0_in[(size_t)grow * Hc + j];   // rare (2 rows/batch)
            *(unsigned short*)(Cs + cs_off(row, j >> 3) + (j & 7) * 2)        = bfu(cw);
            *(unsigned short*)(Cs + cs_off(row, 16 + (j >> 3)) + (j & 7) * 2) = bfu(hw);
        }
    }
    __syncthreads();
    // Cs -> contrib cols 0..255 (coalesced 16B stores)
    #pragma unroll
    for (int i = 0; i < 4; ++i) {
        const int idx = i * 512 + t;
        const int r = idx >> 5, u = idx & 31;
        short8 v = *(const short8*)(Cs + cs_off(r, u));
        *(short8*)(contrib + (size_t)(row0 + r) * H4c + u * 8) = v;
    }
#undef STAGE0
}

// ---------------------------------------------------------------------------
// gemm1: A = [h0n (bf16 from contrib cols 128..255) | h1 (f32->bf16)] via
// chunked dbuf staging. Epilogue: LSTM cell 1 -> contrib[:,256:512] +
// MFMA decision head: E[64x512] @ DF[512x16(4 used)] split across waves
// (w<4: k 0..255 from global contrib; w>=4: k 256..511 from Cs), halves
// combined in the dead Ab buffer, 64-thread softmax finish.
// ---------------------------------------------------------------------------
__global__ __launch_bounds__(512, 4) void gemm1_kernel(
    const unsigned short* __restrict__ contrib_r, const float* __restrict__ c1_in,
    const float* __restrict__ h1_in,
    const unsigned short* __restrict__ W1F, const float* __restrict__ b1,
    const unsigned short* __restrict__ DF,
    const float* __restrict__ rbv, const float* __restrict__ bbv,
    const float* __restrict__ ip_in,
    const int* __restrict__ exit_i, const int* __restrict__ raise_i,
    unsigned short* __restrict__ contrib, float* __restrict__ w_all)
{
    __shared__ __align__(16) char Ab[10240];   // A dbuf; later P0/P1 partials
    __shared__ __align__(16) char Cs[32768];   // 64 rows x 256 bf16 restage

    const int t    = threadIdx.x;
    const int w    = t >> 6, l = t & 63, lr = l & 15, lg = l >> 4;
    const int row0 = blockIdx.x * 64;
    const int bidx = row0 >> 11;
    const int eb   = exit_i[bidx];
    const int rbn  = raise_i[bidx];
    const int j    = w * 16 + lr;

    const int srow = t >> 3, sfq = t & 7;
    // chunk c: c<4 -> h0n bf16 from contrib cols 128+c*32.. ; c>=4 -> h1 f32
#define STAGE1(c, bi)                                                          \
    {                                                                          \
        if ((c) < 4) {                                                         \
            ushort4 v = *(const ushort4*)(contrib_r                            \
                + (size_t)(row0 + srow) * H4c + 128 + ((c) & 3) * 32 + sfq * 4); \
            *(ushort4*)(Ab + a_off(bi, srow, sfq * 8)) = v;                    \
        } else {                                                               \
            const float* sp = h1_in + (size_t)(row0 + srow) * Hc               \
                + ((c) & 3) * 32 + sfq * 4;                                    \
            float4 v = *(const float4*)sp;                                     \
            uint2 b2 = { cvtpk(v.x, v.y), cvtpk(v.z, v.w) };                   \
            *(uint2*)(Ab + a_off(bi, srow, sfq * 8)) = b2;                     \
        }                                                                      \
    }

    f32x4 acc[4][4];
    #pragma unroll
    for (int g = 0; g < 4; ++g) {
        float bv = b1[g * 128 + j];
        f32x4 vv = {bv, bv, bv, bv};
        #pragma unroll
        for (int mt = 0; mt < 4; ++mt) acc[mt][g] = vv;
    }

    STAGE1(0, 0);
    short8 bn[4];
    #pragma unroll
    for (int g = 0; g < 4; ++g)
        bn[g] = *(const short8*)(W1F + ((size_t)((g * 8 + w) * 8) * 64 + l) * 8);
    #pragma unroll
    for (int c = 0; c < 8; ++c) {
        __syncthreads();
        short8 bc[4];
        #pragma unroll
        for (int g = 0; g < 4; ++g) bc[g] = bn[g];
        if (c < 7) {
            STAGE1(c + 1, (c + 1) & 1);
            #pragma unroll
            for (int g = 0; g < 4; ++g)
                bn[g] = *(const short8*)(W1F + ((size_t)((g * 8 + w) * 8 + c + 1) * 64 + l) * 8);
        }
        short8 a[4];
        #pragma unroll
        for (int mt = 0; mt < 4; ++mt)
            a[mt] = *(const short8*)(Ab + a_off(c & 1, mt * 16 + lr, lg * 16));
        #pragma unroll
        for (int mt = 0; mt < 4; ++mt)
            #pragma unroll
            for (int g = 0; g < 4; ++g)
                acc[mt][g] = __builtin_amdgcn_mfma_f32_16x16x32_bf16(
                    a[mt], bc[g], acc[mt][g], 0, 0, 0);
    }

    // ---- epilogue: LSTM cell 1 -> Cs ----
    #pragma unroll
    for (int mt = 0; mt < 4; ++mt) {
        #pragma unroll
        for (int rr = 0; rr < 4; ++rr) {
            const int row  = mt * 16 + lg * 4 + rr;
            const int grow = row0 + row;
            const int n    = grow & (Nc - 1);
            float cold = c1_in[(size_t)grow * Hc + j];
            float ig = sigf(acc[mt][0][rr]);
            float fg = sigf(acc[mt][1][rr]);
            float gv = tanh_(acc[mt][2][rr]);
            float og = sigf(acc[mt][3][rr]);
            float cn = fg * cold + ig * gv;
            float hn = og * tanh_(cn);
            const bool keep = (n == eb) || (n == rbn);
            float cw = keep ? cold : cn;
            float hw = hn;
            if (keep) hw = h1_in[(size_t)grow * Hc + j];   // rare
            *(unsigned short*)(Cs + cs_off(row, j >> 3) + (j & 7) * 2)        = bfu(cw);
            *(unsigned short*)(Cs + cs_off(row, 16 + (j >> 3)) + (j & 7) * 2) = bfu(hw);
        }
    }
    __syncthreads();   // all Ab reads done; Cs filled
    // Cs -> contrib cols 256..511 (coalesced)
    #pragma unroll
    for (int i = 0; i < 4; ++i) {
        const int idx = i * 512 + t;
        const int r = idx >> 5, u = idx & 31;
        short8 v = *(const short8*)(Cs + cs_off(r, u));
        *(short8*)(contrib + (size_t)(row0 + r) * H4c + 256 + u * 8) = v;
    }

    // ---- MFMA decision head ----
    // waves 0..3: row-tile mt=w, k 0..255 from global contrib (gemm0, L3-hot)
    // waves 4..7: row-tile mt=w-4, k 256..511 from Cs (main-loop A pattern)
    {
        const int mt = w & 3;
        f32x4 dacc = {0.f, 0.f, 0.f, 0.f};
        if (w < 4) {
            #pragma unroll
            for (int ks = 0; ks < 8; ++ks) {
                short8 a = *(const short8*)(contrib_r
                    + (size_t)(row0 + mt * 16 + lr) * H4c + ks * 32 + lg * 8);
                short8 b = *(const short8*)(DF + ((size_t)ks * 64 + l) * 8);
                dacc = __builtin_amdgcn_mfma_f32_16x16x32_bf16(a, b, dacc, 0, 0, 0);
            }
        } else {
            #pragma unroll
            for (int ks = 0; ks < 8; ++ks) {
                short8 a = *(const short8*)(Cs + cs_off(mt * 16 + lr, ks * 4 + lg));
                short8 b = *(const short8*)(DF + ((size_t)(8 + ks) * 64 + l) * 8);
                dacc = __builtin_amdgcn_mfma_f32_16x16x32_bf16(a, b, dacc, 0, 0, 0);
            }
        }
        // C layout: col = lane&15, row = (lane>>4)*4 + reg. Store cols 0..3.
        float* P = (float*)Ab;            // P0[64][4] | P1[64][4] (2 KB, Ab dead)
        if (lr < 4) {
            float* Ph = P + (w < 4 ? 0 : 256);
            #pragma unroll
            for (int reg = 0; reg < 4; ++reg)
                Ph[(mt * 16 + lg * 4 + reg) * 4 + lr] = dacc[reg];
        }
        __syncthreads();
        if (t < 64) {
            const int grow = row0 + t;
            const int n    = grow & (Nc - 1);
            float pr0 = P[t * 4 + 0] + P[256 + t * 4 + 0] + rbv[0];
            float pr1 = P[t * 4 + 1] + P[256 + t * 4 + 1] + rbv[1];
            float pb0 = P[t * 4 + 2] + P[256 + t * 4 + 2] + bbv[0];
            float pb1 = P[t * 4 + 3] + P[256 + t * 4 + 3] + bbv[1];
            float m  = fmaxf(pr0, pr1);
            float z0 = __expf(pr0 - m), z1 = __expf(pr1 - m);
            float inv = 1.f / (z0 + z1);
            float praise = z0 * inv, pno = z1 * inv;
            if (n == eb) { praise = 0.f; pno = 1.f; }
            float mm = fmaxf(pb0, pb1);
            float y0 = __expf(pb0 - mm), y1 = __expf(pb1 - mm);
            float binv = 1.f / (y0 + y1);
            float ipv = ip_in[grow];
            w_all[grow]            = praise * ipv;
            w_all[BNc + grow]      = pno * y0 * binv * ipv;
            w_all[2 * BNc + grow]  = pno * y1 * binv * ipv;
        }
    }
#undef STAGE1
}

// ---------------------------------------------------------------------------
// Invert the scatter into per-target linked lists. e = row*4 + type.
// ---------------------------------------------------------------------------
__global__ __launch_bounds__(256) void build_kernel(
    const int* __restrict__ t_idx, const int* __restrict__ f_idx,
    const int* __restrict__ r_idx, int* __restrict__ head, int* __restrict__ nxt)
{
    const int row  = blockIdx.x * 256 + threadIdx.x;
    const int base = (row >> 11) << 11;
    const int e0 = row * 4;
    int o;
    o = atomicExch(&head[base + r_idx[row]], e0);     nxt[e0]     = o;
    o = atomicExch(&head[base + t_idx[row]], e0 + 1); nxt[e0 + 1] = o;
    o = atomicExch(&head[base + f_idx[row]], e0 + 2); nxt[e0 + 2] = o;
}

// ---------------------------------------------------------------------------
// Gather: one wave per target (b,m). Dword (2 x bf16) loads per lane —
// lane l handles elements q*128 + 2l, 2l+1 (q = comp index 0..3).
// ---------------------------------------------------------------------------
__global__ __launch_bounds__(256) void gather_kernel(
    const unsigned short* __restrict__ contrib, const float* __restrict__ w_all,
    const int* __restrict__ head, const int* __restrict__ nxt,
    const float* __restrict__ c0_in, const float* __restrict__ h0_in,
    const float* __restrict__ c1_in, const float* __restrict__ h1_in,
    const float* __restrict__ ip_in,
    const int* __restrict__ cstep, const int* __restrict__ slim,
    float* __restrict__ out)
{
    const int gtid = blockIdx.x * 256 + threadIdx.x;
    const int wid  = gtid >> 6;
    const int l    = gtid & 63;
    const int bidx = wid >> 11;

    float ax[4] = {0.f, 0.f, 0.f, 0.f};
    float ay[4] = {0.f, 0.f, 0.f, 0.f};
    float ipsum = 0.f;

    int e = head[wid];
    while (e >= 0) {
        const int src = e >> 2;
        const float w = w_all[(e & 3) * BNc + src];
        const unsigned* crow = (const unsigned*)(contrib + (size_t)src * 512);
        #pragma unroll
        for (int q = 0; q < 4; ++q) {
            unsigned pv = crow[q * 64 + l];   // elements q*128+2l, q*128+2l+1
            ax[q] += w * bf2f((unsigned short)(pv & 0xFFFFu));
            ay[q] += w * bf2f((unsigned short)(pv >> 16));
        }
        ipsum += w;
        e = nxt[e];
    }

    const bool live = cstep[bidx] < slim[bidx];
    float* orow = out + (size_t)wid * 513;
    if (live) {
        const float inv = 1.f / (ipsum + 1e-7f);
        #pragma unroll
        for (int q = 0; q < 4; ++q) {
            const int idx0 = q * 128 + 2 * l;
            orow[idx0]     = ax[q] * inv;
            orow[idx0 + 1] = ay[q] * inv;
        }
        if (l == 0) orow[512] = ipsum;
    } else {
        #pragma unroll
        for (int q = 0; q < 4; ++q) {
            const float* p = q == 0 ? c0_in : q == 1 ? h0_in
                           : q == 2 ? c1_in : h1_in;
            float2 v = *(const float2*)(p + (size_t)wid * Hc + 2 * l);
            const int idx0 = q * 128 + 2 * l;
            orow[idx0]     = v.x;
            orow[idx0 + 1] = v.y;
        }
        if (l == 0) orow[512] = ip_in[wid];
    }
}

extern "C" void kernel_launch(void* const* d_in, const int* in_sizes, int n_in,
                              void* d_out, int out_size, void* d_ws, size_t ws_size,
                              hipStream_t stream) {
    const float* x     = (const float*)d_in[0];
    const float* c0    = (const float*)d_in[1];
    const float* h0    = (const float*)d_in[2];
    const float* c1    = (const float*)d_in[3];
    const float* h1    = (const float*)d_in[4];
    const float* ip    = (const float*)d_in[5];
    const float* Wx0   = (const float*)d_in[6];
    const float* Wh0   = (const float*)d_in[7];
    const float* b0    = (const float*)d_in[8];
    const float* Wx1   = (const float*)d_in[9];
    const float* Wh1   = (const float*)d_in[10];
    const float* b1    = (const float*)d_in[11];
    const float* rW    = (const float*)d_in[12];
    const float* rb    = (const float*)d_in[13];
    const float* bW    = (const float*)d_in[14];
    const float* bb    = (const float*)d_in[15];
    const int* t_idx   = (const int*)d_in[16];
    const int* f_idx   = (const int*)d_in[17];
    const int* r_idx   = (const int*)d_in[18];
    const int* exit_i  = (const int*)d_in[19];
    const int* raise_i = (const int*)d_in[20];
    const int* cstep   = (const int*)d_in[21];
    const int* slim    = (const int*)d_in[22];
    float* out = (float*)d_out;

    // workspace layout
    unsigned short* contrib = (unsigned short*)d_ws;            // BN*512 bf16 (64 MiB)
    unsigned short* W0F = contrib + (size_t)BNc * 512;          // 512*256 bf16
    unsigned short* W1F = W0F + 512 * 256;
    unsigned short* DF  = W1F + 512 * 256;                      // 16*64*8 bf16 (16 KiB)
    float* w_all = (float*)(DF + 16 * 64 * 8);                  // 3*BN f32
    int*   head  = (int*)(w_all + 3 * (size_t)BNc);             // BN int
    int*   nxt   = head + BNc;                                  // 4*BN int

    prep_kernel<<<64, 256, 0, stream>>>(Wx0, Wh0, Wx1, Wh1, rW, bW,
                                        W0F, W1F, DF, head);
    build_kernel<<<BNc / 256, 256, 0, stream>>>(t_idx, f_idx, r_idx, head, nxt);
    gemm0_kernel<<<BNc / 64, 512, 0, stream>>>(x, c0, h0, W0F, b0,
                                               exit_i, raise_i, contrib);
    gemm1_kernel<<<BNc / 64, 512, 0, stream>>>(contrib, c1, h1, W1F, b1,
                                               DF, rb, bb, ip,
                                               exit_i, raise_i, contrib, w_all);
    gather_kernel<<<BNc / 4, 256, 0, stream>>>(contrib, w_all, head, nxt,
                                               c0, h0, c1, h1, ip, cstep, slim, out);
}

// Round 19
// 178.867 us; speedup vs baseline: 1.2010x; 1.0321x over previous
//
#include <hip/hip_runtime.h>
#include <hip/hip_bf16.h>

// Problem constants (match reference setup_inputs)
constexpr int Bc  = 32;
constexpr int Nc  = 2048;
constexpr int Hc  = 128;
constexpr int H4c = 512;
constexpr int BNc = Bc * Nc;   // 65536 rows

typedef __attribute__((ext_vector_type(8))) short short8;
typedef __attribute__((ext_vector_type(4))) float f32x4;

// clamp-free: v_exp saturates to 0/inf, forms below stay finite/correct
__device__ __forceinline__ float sigf(float x)  { return 1.f / (1.f + __expf(-x)); }
__device__ __forceinline__ float tanh_(float x) { return 1.f - 2.f / (__expf(2.f * x) + 1.f); }

// f32 -> bf16 bits (RNE)
__device__ __forceinline__ unsigned short bfu(float f) {
    union { float f; unsigned u; } a; a.f = f;
    unsigned u = a.u;
    return (unsigned short)((u + 0x7FFFu + ((u >> 16) & 1u)) >> 16);
}
__device__ __forceinline__ float bf2f(unsigned short u) {
    union { unsigned u; float f; } a; a.u = ((unsigned)u) << 16;
    return a.f;
}
// HW packed conversion: lo -> bits[15:0], hi -> bits[31:16], RNE
__device__ __forceinline__ unsigned cvtpk(float lo, float hi) {
    unsigned r;
    asm("v_cvt_pk_bf16_f32 %0, %1, %2" : "=v"(r) : "v"(lo), "v"(hi));
    return r;
}

// A-tile (dbuf staging): row stride 80 B (64 B data + 16 pad).
__device__ __forceinline__ int a_off(int buf, int row, int byte) {
    return buf * 5120 + row * 80 + byte;
}
// Cs tile: 64 rows x 32 units of 16 B, XOR swizzle.
__device__ __forceinline__ int cs_off(int row, int unit) {
    return row * 512 + ((unit ^ (row & 7)) << 4);
}

// ---------------------------------------------------------------------------
// Weight prep -> fragment-major: WF[ct][ks][lane][e], col = ct*16 + (lane&15),
// k = ks*32 + (lane>>4)*8 + e. Also clears head[] (-1) and builds the
// decision-head B-operand DF[16 ks][64 lanes][8] bf16 where logical col
// (lane&15): 0=rW[:,0], 1=rW[:,1], 2=bW[:,0], 3=bW[:,1], 4..15 = 0.
// ---------------------------------------------------------------------------
__global__ __launch_bounds__(256) void prep_kernel(
    const float* __restrict__ Wx0, const float* __restrict__ Wh0,
    const float* __restrict__ Wx1, const float* __restrict__ Wh1,
    const float* __restrict__ rW, const float* __restrict__ bW,
    unsigned short* __restrict__ W0F, unsigned short* __restrict__ W1F,
    unsigned short* __restrict__ DF, int* __restrict__ head)
{
    int idx = blockIdx.x * 256 + threadIdx.x;   // 0..16383 = (ct,ks,lane)
    int4 m1 = { -1, -1, -1, -1 };
    ((int4*)head)[idx] = m1;                    // 16384 x int4 = 65536 ints

    int ct = idx >> 9, ks = (idx >> 6) & 7, lane = idx & 63;
    int col = ct * 16 + (lane & 15);
    unsigned short* p0 = W0F + (size_t)idx * 8;
    unsigned short* p1 = W1F + (size_t)idx * 8;
    #pragma unroll
    for (int e = 0; e < 8; ++e) {
        int k = ks * 32 + (lane >> 4) * 8 + e;
        float v0 = (k < 128) ? Wx0[k * 512 + col] : Wh0[(k - 128) * 512 + col];
        float v1 = (k < 128) ? Wx1[k * 512 + col] : Wh1[(k - 128) * 512 + col];
        p0[e] = bfu(v0);
        p1[e] = bfu(v1);
    }

    // DF: 16 ks x 64 lanes (first 1024 global threads)
    if (idx < 1024) {
        int dks = idx >> 6, dl = idx & 63;
        int dcol = dl & 15;
        int kb   = dks * 32 + (dl >> 4) * 8;
        unsigned short* pd = DF + (size_t)idx * 8;
        #pragma unroll
        for (int e = 0; e < 8; ++e) {
            int k = kb + e;
            float v = 0.f;
            if (dcol < 2)      v = rW[k * 2 + dcol];
            else if (dcol < 4) v = bW[k * 2 + (dcol - 2)];
            pd[e] = bfu(v);
        }
    }
}

// ---------------------------------------------------------------------------
// gemm0: 512 thr / 8 waves / 64 rows x all 512 cols — champion structure.
// Chunked dbuf A staging, B register-prefetched fragment-major, one barrier
// per chunk. Epilogue: LSTM cell 0 -> Cs -> contrib[:,0:256] + MFMA dec-head
// FIRST half (k 0..255 from Cs, waves 0..3) -> w_part[BN] float4.
// ---------------------------------------------------------------------------
__global__ __launch_bounds__(512, 4) void gemm0_kernel(
    const float* __restrict__ x_in,  const float* __restrict__ c0_in,
    const float* __restrict__ h0_in,
    const unsigned short* __restrict__ W0F, const float* __restrict__ b0,
    const unsigned short* __restrict__ DF,
    const int* __restrict__ exit_i, const int* __restrict__ raise_i,
    unsigned short* __restrict__ contrib, float4* __restrict__ w_part)
{
    __shared__ __align__(16) char Ab[10240];   // A dbuf; later P partials
    __shared__ __align__(16) char Cs[32768];   // 64 rows x 256 bf16 restage

    const int t    = threadIdx.x;
    const int w    = t >> 6, l = t & 63, lr = l & 15, lg = l >> 4;
    const int row0 = blockIdx.x * 64;
    const int bidx = row0 >> 11;
    const int eb   = exit_i[bidx];
    const int rbn  = raise_i[bidx];
    const int j    = w * 16 + lr;

    const int srow = t >> 3, sfq = t & 7;
#define STAGE0(c, bi)                                                          \
    {                                                                          \
        const float* sp = ((c) < 4 ? x_in : h0_in)                             \
            + (size_t)(row0 + srow) * Hc + ((c) & 3) * 32 + sfq * 4;           \
        float4 v = *(const float4*)sp;                                         \
        uint2 b2 = { cvtpk(v.x, v.y), cvtpk(v.z, v.w) };                       \
        *(uint2*)(Ab + a_off(bi, srow, sfq * 8)) = b2;                         \
    }

    f32x4 acc[4][4];
    #pragma unroll
    for (int g = 0; g < 4; ++g) {
        float bv = b0[g * 128 + j];
        f32x4 vv = {bv, bv, bv, bv};
        #pragma unroll
        for (int mt = 0; mt < 4; ++mt) acc[mt][g] = vv;
    }

    STAGE0(0, 0);
    short8 bn[4];
    #pragma unroll
    for (int g = 0; g < 4; ++g)
        bn[g] = *(const short8*)(W0F + ((size_t)((g * 8 + w) * 8) * 64 + l) * 8);
    #pragma unroll
    for (int c = 0; c < 8; ++c) {
        __syncthreads();
        short8 bc[4];
        #pragma unroll
        for (int g = 0; g < 4; ++g) bc[g] = bn[g];
        if (c < 7) {
            STAGE0(c + 1, (c + 1) & 1);
            #pragma unroll
            for (int g = 0; g < 4; ++g)
                bn[g] = *(const short8*)(W0F + ((size_t)((g * 8 + w) * 8 + c + 1) * 64 + l) * 8);
        }
        short8 a[4];
        #pragma unroll
        for (int mt = 0; mt < 4; ++mt)
            a[mt] = *(const short8*)(Ab + a_off(c & 1, mt * 16 + lr, lg * 16));
        #pragma unroll
        for (int mt = 0; mt < 4; ++mt)
            #pragma unroll
            for (int g = 0; g < 4; ++g)
                acc[mt][g] = __builtin_amdgcn_mfma_f32_16x16x32_bf16(
                    a[mt], bc[g], acc[mt][g], 0, 0, 0);
    }

    // ---- epilogue: LSTM cell 0 -> Cs (inline loads, no arrays) ----
    #pragma unroll
    for (int mt = 0; mt < 4; ++mt) {
        #pragma unroll
        for (int rr = 0; rr < 4; ++rr) {
            const int row  = mt * 16 + lg * 4 + rr;
            const int grow = row0 + row;
            const int n    = grow & (Nc - 1);
            float cold = c0_in[(size_t)grow * Hc + j];
            float ig = sigf(acc[mt][0][rr]);
            float fg = sigf(acc[mt][1][rr]);
            float gv = tanh_(acc[mt][2][rr]);
            float og = sigf(acc[mt][3][rr]);
            float cn = fg * cold + ig * gv;
            float hn = og * tanh_(cn);
            const bool keep = (n == eb) || (n == rbn);
            float cw = keep ? cold : cn;
            float hw = hn;
            if (keep) hw = h0_in[(size_t)grow * Hc + j];   // rare (2 rows/batch)
            *(unsigned short*)(Cs + cs_off(row, j >> 3) + (j & 7) * 2)        = bfu(cw);
            *(unsigned short*)(Cs + cs_off(row, 16 + (j >> 3)) + (j & 7) * 2) = bfu(hw);
        }
    }
    __syncthreads();   // Cs ready; Ab dead (last read pre-epilogue)
    // Cs -> contrib cols 0..255 (coalesced 16B stores)
    #pragma unroll
    for (int i = 0; i < 4; ++i) {
        const int idx = i * 512 + t;
        const int r = idx >> 5, u = idx & 31;
        short8 v = *(const short8*)(Cs + cs_off(r, u));
        *(short8*)(contrib + (size_t)(row0 + r) * H4c + u * 8) = v;
    }

    // ---- MFMA dec-head first half: waves 0..3, A = Cs (cols 0..255) ----
    {
        const int mt = w & 3;
        f32x4 dacc = {0.f, 0.f, 0.f, 0.f};
        if (w < 4) {
            #pragma unroll
            for (int ks = 0; ks < 8; ++ks) {
                short8 a = *(const short8*)(Cs + cs_off(mt * 16 + lr, ks * 4 + lg));
                short8 b = *(const short8*)(DF + ((size_t)ks * 64 + l) * 8);
                dacc = __builtin_amdgcn_mfma_f32_16x16x32_bf16(a, b, dacc, 0, 0, 0);
            }
        }
        float* P = (float*)Ab;            // P[64][4] (1 KB, Ab dead)
        if (w < 4 && lr < 4) {
            #pragma unroll
            for (int reg = 0; reg < 4; ++reg)
                P[(mt * 16 + lg * 4 + reg) * 4 + lr] = dacc[reg];
        }
        __syncthreads();
        if (t < 64)
            w_part[row0 + t] = *(const float4*)&P[t * 4];
    }
#undef STAGE0
}

// ---------------------------------------------------------------------------
// gemm1: A = [h0n (bf16 from contrib cols 128..255) | h1 (f32->bf16)] via
// chunked dbuf staging. Epilogue: LSTM cell 1 -> contrib[:,256:512] +
// MFMA dec-head SECOND half (k 256..511 from Cs, waves 4..7) combined with
// w_part — zero global contrib A-reads in the head.
// ---------------------------------------------------------------------------
__global__ __launch_bounds__(512, 4) void gemm1_kernel(
    const unsigned short* __restrict__ contrib_r, const float* __restrict__ c1_in,
    const float* __restrict__ h1_in,
    const unsigned short* __restrict__ W1F, const float* __restrict__ b1,
    const unsigned short* __restrict__ DF,
    const float* __restrict__ rbv, const float* __restrict__ bbv,
    const float* __restrict__ ip_in, const float4* __restrict__ w_part,
    const int* __restrict__ exit_i, const int* __restrict__ raise_i,
    unsigned short* __restrict__ contrib, float* __restrict__ w_all)
{
    __shared__ __align__(16) char Ab[10240];   // A dbuf; later P partials
    __shared__ __align__(16) char Cs[32768];   // 64 rows x 256 bf16 restage

    const int t    = threadIdx.x;
    const int w    = t >> 6, l = t & 63, lr = l & 15, lg = l >> 4;
    const int row0 = blockIdx.x * 64;
    const int bidx = row0 >> 11;
    const int eb   = exit_i[bidx];
    const int rbn  = raise_i[bidx];
    const int j    = w * 16 + lr;

    const int srow = t >> 3, sfq = t & 7;
    // chunk c: c<4 -> h0n bf16 from contrib cols 128+c*32.. ; c>=4 -> h1 f32
#define STAGE1(c, bi)                                                          \
    {                                                                          \
        if ((c) < 4) {                                                         \
            ushort4 v = *(const ushort4*)(contrib_r                            \
                + (size_t)(row0 + srow) * H4c + 128 + ((c) & 3) * 32 + sfq * 4); \
            *(ushort4*)(Ab + a_off(bi, srow, sfq * 8)) = v;                    \
        } else {                                                               \
            const float* sp = h1_in + (size_t)(row0 + srow) * Hc               \
                + ((c) & 3) * 32 + sfq * 4;                                    \
            float4 v = *(const float4*)sp;                                     \
            uint2 b2 = { cvtpk(v.x, v.y), cvtpk(v.z, v.w) };                   \
            *(uint2*)(Ab + a_off(bi, srow, sfq * 8)) = b2;                     \
        }                                                                      \
    }

    f32x4 acc[4][4];
    #pragma unroll
    for (int g = 0; g < 4; ++g) {
        float bv = b1[g * 128 + j];
        f32x4 vv = {bv, bv, bv, bv};
        #pragma unroll
        for (int mt = 0; mt < 4; ++mt) acc[mt][g] = vv;
    }

    STAGE1(0, 0);
    short8 bn[4];
    #pragma unroll
    for (int g = 0; g < 4; ++g)
        bn[g] = *(const short8*)(W1F + ((size_t)((g * 8 + w) * 8) * 64 + l) * 8);
    #pragma unroll
    for (int c = 0; c < 8; ++c) {
        __syncthreads();
        short8 bc[4];
        #pragma unroll
        for (int g = 0; g < 4; ++g) bc[g] = bn[g];
        if (c < 7) {
            STAGE1(c + 1, (c + 1) & 1);
            #pragma unroll
            for (int g = 0; g < 4; ++g)
                bn[g] = *(const short8*)(W1F + ((size_t)((g * 8 + w) * 8 + c + 1) * 64 + l) * 8);
        }
        short8 a[4];
        #pragma unroll
        for (int mt = 0; mt < 4; ++mt)
            a[mt] = *(const short8*)(Ab + a_off(c & 1, mt * 16 + lr, lg * 16));
        #pragma unroll
        for (int mt = 0; mt < 4; ++mt)
            #pragma unroll
            for (int g = 0; g < 4; ++g)
                acc[mt][g] = __builtin_amdgcn_mfma_f32_16x16x32_bf16(
                    a[mt], bc[g], acc[mt][g], 0, 0, 0);
    }

    // ---- epilogue: LSTM cell 1 -> Cs ----
    #pragma unroll
    for (int mt = 0; mt < 4; ++mt) {
        #pragma unroll
        for (int rr = 0; rr < 4; ++rr) {
            const int row  = mt * 16 + lg * 4 + rr;
            const int grow = row0 + row;
            const int n    = grow & (Nc - 1);
            float cold = c1_in[(size_t)grow * Hc + j];
            float ig = sigf(acc[mt][0][rr]);
            float fg = sigf(acc[mt][1][rr]);
            float gv = tanh_(acc[mt][2][rr]);
            float og = sigf(acc[mt][3][rr]);
            float cn = fg * cold + ig * gv;
            float hn = og * tanh_(cn);
            const bool keep = (n == eb) || (n == rbn);
            float cw = keep ? cold : cn;
            float hw = hn;
            if (keep) hw = h1_in[(size_t)grow * Hc + j];   // rare
            *(unsigned short*)(Cs + cs_off(row, j >> 3) + (j & 7) * 2)        = bfu(cw);
            *(unsigned short*)(Cs + cs_off(row, 16 + (j >> 3)) + (j & 7) * 2) = bfu(hw);
        }
    }
    __syncthreads();   // all Ab reads done; Cs filled
    // Cs -> contrib cols 256..511 (coalesced)
    #pragma unroll
    for (int i = 0; i < 4; ++i) {
        const int idx = i * 512 + t;
        const int r = idx >> 5, u = idx & 31;
        short8 v = *(const short8*)(Cs + cs_off(r, u));
        *(short8*)(contrib + (size_t)(row0 + r) * H4c + 256 + u * 8) = v;
    }

    // ---- MFMA dec-head second half: waves 4..7, A = Cs (cols 256..511) ----
    {
        const int mt = w & 3;
        f32x4 dacc = {0.f, 0.f, 0.f, 0.f};
        if (w >= 4) {
            #pragma unroll
            for (int ks = 0; ks < 8; ++ks) {
                short8 a = *(const short8*)(Cs + cs_off(mt * 16 + lr, ks * 4 + lg));
                short8 b = *(const short8*)(DF + ((size_t)(8 + ks) * 64 + l) * 8);
                dacc = __builtin_amdgcn_mfma_f32_16x16x32_bf16(a, b, dacc, 0, 0, 0);
            }
        }
        float* P = (float*)Ab;            // P[64][4] (1 KB, Ab dead)
        if (w >= 4 && lr < 4) {
            #pragma unroll
            for (int reg = 0; reg < 4; ++reg)
                P[(mt * 16 + lg * 4 + reg) * 4 + lr] = dacc[reg];
        }
        __syncthreads();
        if (t < 64) {
            const int grow = row0 + t;
            const int n    = grow & (Nc - 1);
            float4 wp = w_part[grow];
            float pr0 = P[t * 4 + 0] + wp.x + rbv[0];
            float pr1 = P[t * 4 + 1] + wp.y + rbv[1];
            float pb0 = P[t * 4 + 2] + wp.z + bbv[0];
            float pb1 = P[t * 4 + 3] + wp.w + bbv[1];
            float m  = fmaxf(pr0, pr1);
            float z0 = __expf(pr0 - m), z1 = __expf(pr1 - m);
            float inv = 1.f / (z0 + z1);
            float praise = z0 * inv, pno = z1 * inv;
            if (n == eb) { praise = 0.f; pno = 1.f; }
            float mm = fmaxf(pb0, pb1);
            float y0 = __expf(pb0 - mm), y1 = __expf(pb1 - mm);
            float binv = 1.f / (y0 + y1);
            float ipv = ip_in[grow];
            w_all[grow]            = praise * ipv;
            w_all[BNc + grow]      = pno * y0 * binv * ipv;
            w_all[2 * BNc + grow]  = pno * y1 * binv * ipv;
        }
    }
#undef STAGE1
}

// ---------------------------------------------------------------------------
// Invert the scatter into per-target linked lists. e = row*4 + type.
// ---------------------------------------------------------------------------
__global__ __launch_bounds__(256) void build_kernel(
    const int* __restrict__ t_idx, const int* __restrict__ f_idx,
    const int* __restrict__ r_idx, int* __restrict__ head, int* __restrict__ nxt)
{
    const int row  = blockIdx.x * 256 + threadIdx.x;
    const int base = (row >> 11) << 11;
    const int e0 = row * 4;
    int o;
    o = atomicExch(&head[base + r_idx[row]], e0);     nxt[e0]     = o;
    o = atomicExch(&head[base + t_idx[row]], e0 + 1); nxt[e0 + 1] = o;
    o = atomicExch(&head[base + f_idx[row]], e0 + 2); nxt[e0 + 2] = o;
}

// ---------------------------------------------------------------------------
// Gather: one wave per target (b,m). Dword (2 x bf16) loads per lane —
// lane l handles elements q*128 + 2l, 2l+1 (q = comp index 0..3).
// ---------------------------------------------------------------------------
__global__ __launch_bounds__(256) void gather_kernel(
    const unsigned short* __restrict__ contrib, const float* __restrict__ w_all,
    const int* __restrict__ head, const int* __restrict__ nxt,
    const float* __restrict__ c0_in, const float* __restrict__ h0_in,
    const float* __restrict__ c1_in, const float* __restrict__ h1_in,
    const float* __restrict__ ip_in,
    const int* __restrict__ cstep, const int* __restrict__ slim,
    float* __restrict__ out)
{
    const int gtid = blockIdx.x * 256 + threadIdx.x;
    const int wid  = gtid >> 6;
    const int l    = gtid & 63;
    const int bidx = wid >> 11;

    float ax[4] = {0.f, 0.f, 0.f, 0.f};
    float ay[4] = {0.f, 0.f, 0.f, 0.f};
    float ipsum = 0.f;

    int e = head[wid];
    while (e >= 0) {
        const int src = e >> 2;
        const float w = w_all[(e & 3) * BNc + src];
        const unsigned* crow = (const unsigned*)(contrib + (size_t)src * 512);
        #pragma unroll
        for (int q = 0; q < 4; ++q) {
            unsigned pv = crow[q * 64 + l];   // elements q*128+2l, q*128+2l+1
            ax[q] += w * bf2f((unsigned short)(pv & 0xFFFFu));
            ay[q] += w * bf2f((unsigned short)(pv >> 16));
        }
        ipsum += w;
        e = nxt[e];
    }

    const bool live = cstep[bidx] < slim[bidx];
    float* orow = out + (size_t)wid * 513;
    if (live) {
        const float inv = 1.f / (ipsum + 1e-7f);
        #pragma unroll
        for (int q = 0; q < 4; ++q) {
            const int idx0 = q * 128 + 2 * l;
            orow[idx0]     = ax[q] * inv;
            orow[idx0 + 1] = ay[q] * inv;
        }
        if (l == 0) orow[512] = ipsum;
    } else {
        #pragma unroll
        for (int q = 0; q < 4; ++q) {
            const float* p = q == 0 ? c0_in : q == 1 ? h0_in
                           : q == 2 ? c1_in : h1_in;
            float2 v = *(const float2*)(p + (size_t)wid * Hc + 2 * l);
            const int idx0 = q * 128 + 2 * l;
            orow[idx0]     = v.x;
            orow[idx0 + 1] = v.y;
        }
        if (l == 0) orow[512] = ip_in[wid];
    }
}

extern "C" void kernel_launch(void* const* d_in, const int* in_sizes, int n_in,
                              void* d_out, int out_size, void* d_ws, size_t ws_size,
                              hipStream_t stream) {
    const float* x     = (const float*)d_in[0];
    const float* c0    = (const float*)d_in[1];
    const float* h0    = (const float*)d_in[2];
    const float* c1    = (const float*)d_in[3];
    const float* h1    = (const float*)d_in[4];
    const float* ip    = (const float*)d_in[5];
    const float* Wx0   = (const float*)d_in[6];
    const float* Wh0   = (const float*)d_in[7];
    const float* b0    = (const float*)d_in[8];
    const float* Wx1   = (const float*)d_in[9];
    const float* Wh1   = (const float*)d_in[10];
    const float* b1    = (const float*)d_in[11];
    const float* rW    = (const float*)d_in[12];
    const float* rb    = (const float*)d_in[13];
    const float* bW    = (const float*)d_in[14];
    const float* bb    = (const float*)d_in[15];
    const int* t_idx   = (const int*)d_in[16];
    const int* f_idx   = (const int*)d_in[17];
    const int* r_idx   = (const int*)d_in[18];
    const int* exit_i  = (const int*)d_in[19];
    const int* raise_i = (const int*)d_in[20];
    const int* cstep   = (const int*)d_in[21];
    const int* slim    = (const int*)d_in[22];
    float* out = (float*)d_out;

    // workspace layout
    unsigned short* contrib = (unsigned short*)d_ws;            // BN*512 bf16 (64 MiB)
    unsigned short* W0F = contrib + (size_t)BNc * 512;          // 512*256 bf16
    unsigned short* W1F = W0F + 512 * 256;
    unsigned short* DF  = W1F + 512 * 256;                      // 16*64*8 bf16 (16 KiB)
    float* w_all = (float*)(DF + 16 * 64 * 8);                  // 3*BN f32
    int*   head  = (int*)(w_all + 3 * (size_t)BNc);             // BN int
    int*   nxt   = head + BNc;                                  // 4*BN int
    float4* w_part = (float4*)(nxt + 4 * (size_t)BNc);          // BN float4 (1 MiB)

    prep_kernel<<<64, 256, 0, stream>>>(Wx0, Wh0, Wx1, Wh1, rW, bW,
                                        W0F, W1F, DF, head);
    build_kernel<<<BNc / 256, 256, 0, stream>>>(t_idx, f_idx, r_idx, head, nxt);
    gemm0_kernel<<<BNc / 64, 512, 0, stream>>>(x, c0, h0, W0F, b0, DF,
                                               exit_i, raise_i, contrib, w_part);
    gemm1_kernel<<<BNc / 64, 512, 0, stream>>>(contrib, c1, h1, W1F, b1,
                                               DF, rb, bb, ip, w_part,
                                               exit_i, raise_i, contrib, w_all);
    gather_kernel<<<BNc / 4, 256, 0, stream>>>(contrib, w_all, head, nxt,
                                               c0, h0, c1, h1, ip, cstep, slim, out);
}